// Round 3
// baseline (221.791 us; speedup 1.0000x reference)
//
#include <hip/hip_runtime.h>
#include <math.h>

// ive(v=49.5, z) = exp(-z) * I_v(z) via the uniform (Debye) asymptotic
// expansion DLMF 10.41.3, worked in log2 domain with gfx950 hardware
// transcendentals (v_rsq/v_rcp/v_log/v_exp/v_sqrt — all ~1 ulp):
//
//   x = z/v, q = 1+x^2, t = 1/sqrt(q), p = sqrt(q)
//   e2 = v*log2e*p + v*log2(x/(1+p)) - log2e*z        (exponent, base 2)
//   ive = exp2(e2) * (1/sqrt(2*pi*v)) * sqrt(t) * sum_k u_k(t)/v^k
//
// Accuracy: absmax 9.3e-10 vs 4.3e-9 threshold (R0/R2-verified, 4.6x margin).
//
// Timing context (R0/R2): dur_us includes ~161us of harness poison fills
// (2x 80.4us, 512MiB each — visible as fillBufferAligned in rocprof).
// Kernel portion ~55us vs 42.6us floor (268MB compulsory @ 6.3TB/s copy
// ceiling). R2 added nt loads/stores (-2.6us).
// R3: grid-stride at 2048 blocks (Guideline 11) — 8 blocks/CU x 4 waves
// = full 32-wave occupancy; 16 float4s/thread amortizes address setup and
// lets the loop pipeline next loads under current compute, instead of
// 32768 single-shot blocks with MLP=1 per thread.

typedef float v4f __attribute__((ext_vector_type(4)));

__device__ __forceinline__ float ive_debye(float z) {
    const float inv_v    = (float)(1.0 / 49.5);
    const float c_pref   = 0.05670319f;                  // 1/sqrt(2*pi*49.5)
    const float v_log2e  = 71.41340452f;                 // 49.5 * log2(e)
    const float n_log2e  = -1.4426950408889634f;         // -log2(e)
    const float c1 = (float)(1.0 / (24.0 * 49.5));
    const float c2 = (float)(1.0 / (1152.0 * 49.5 * 49.5));
    const float c3 = (float)(1.0 / (414720.0 * 49.5 * 49.5 * 49.5));
    const float c4 = (float)(1.0 / (39813120.0 * 49.5 * 49.5 * 49.5 * 49.5));

    float x = z * inv_v;
    float q = fmaf(x, x, 1.0f);
    float t = __builtin_amdgcn_rsqf(q);       // 1/sqrt(1+x^2)
    float p = q * t;                           // sqrt(1+x^2)
    float s = t * t;

    // log2(x/(1+p)) via hw rcp + hw log2
    float lg = __builtin_amdgcn_logf(x * __builtin_amdgcn_rcpf(1.0f + p));
    // base-2 exponent: v*log2e*p + v*lg - z*log2e
    float e2 = fmaf(v_log2e, p, fmaf(49.5f, lg, n_log2e * z));

    // u_k(t)/v^k, Horner in s=t^2 (A&S 9.3.9)
    float u1 = c1 * t * fmaf(-5.0f, s, 3.0f);
    float u2 = c2 * s * fmaf(s, fmaf(385.0f, s, -462.0f), 81.0f);
    float u3 = c3 * (t * s) *
               fmaf(s, fmaf(s, fmaf(-425425.0f, s, 765765.0f), -369603.0f), 30375.0f);
    float u4 = c4 * (s * s) *
               fmaf(s, fmaf(s, fmaf(s, fmaf(185910725.0f, s, -446185740.0f),
                                    349922430.0f), -94121676.0f), 4465125.0f);
    float poly = 1.0f + u1 + u2 + u3 + u4;

    float pref = c_pref * __builtin_amdgcn_sqrtf(t);
    return __builtin_amdgcn_exp2f(e2) * pref * poly;
}

__global__ __launch_bounds__(256) void ive_kernel(const float* __restrict__ z,
                                                  float* __restrict__ out,
                                                  int n4, int n) {
    int stride = gridDim.x * blockDim.x;
    for (int i = blockIdx.x * blockDim.x + threadIdx.x; i < n4; i += stride) {
        // touch-once streams: nt load/store skip L2/L3 allocation
        v4f zv = __builtin_nontemporal_load((const v4f*)z + i);
        v4f o;
        o.x = ive_debye(zv.x);
        o.y = ive_debye(zv.y);
        o.z = ive_debye(zv.z);
        o.w = ive_debye(zv.w);
        __builtin_nontemporal_store(o, (v4f*)out + i);
    }
    if (blockIdx.x == 0 && threadIdx.x == 0) {
        for (int j = n4 * 4; j < n; ++j) out[j] = ive_debye(z[j]);
    }
}

extern "C" void kernel_launch(void* const* d_in, const int* in_sizes, int n_in,
                              void* d_out, int out_size, void* d_ws, size_t ws_size,
                              hipStream_t stream) {
    const float* z = (const float*)d_in[0];
    float* out = (float*)d_out;
    int n = in_sizes[0];
    int n4 = n >> 2;
    int threads = 256;
    int blocks = (n4 + threads - 1) / threads;
    if (blocks > 2048) blocks = 2048;   // 8 blocks/CU, grid-stride the rest
    if (blocks < 1) blocks = 1;
    ive_kernel<<<blocks, threads, 0, stream>>>(z, out, n4, n);
}

// Round 4
// 217.720 us; speedup vs baseline: 1.0187x; 1.0187x over previous
//
#include <hip/hip_runtime.h>
#include <math.h>

// ive(v=49.5, z) = exp(-z) * I_v(z) via the uniform (Debye) asymptotic
// expansion DLMF 10.41.3, worked in log2 domain with gfx950 hardware
// transcendentals (v_rsq/v_rcp/v_log/v_exp/v_sqrt — all ~1 ulp):
//
//   x = z/v, q = 1+x^2, t = 1/sqrt(q), p = sqrt(q)
//   e2 = v*log2e*p + v*log2(x/(1+p)) - log2e*z        (exponent, base 2)
//   ive = exp2(e2) * (1/sqrt(2*pi*v)) * sqrt(t) * sum_k u_k(t)/v^k
//
// Accuracy: absmax 9.3e-10 vs 4.3e-9 threshold (R0/R2/R3-verified).
//
// Timing context: dur_us includes ~161us of harness poison fills (2x ~80us,
// 512MiB each, visible as fillBufferAligned in rocprof). Kernel portion
// ~55us vs 42.6us floor (268MB compulsory @ 6.3TB/s copy ceiling).
// R2: nt load/store (-2.6us). R3: grid-stride 2048 blocks REGRESSED +6us
// (serial loop, MLP stayed 1, added branch overhead) — reverted.
// R4: one-shot grid, 2 float4s/thread, BOTH nt loads issued before any
// compute — explicit MLP=2 so the 2nd load's ~900cyc HBM latency hides
// under the 1st quad's compute chain; address setup amortized over 32B.

typedef float v4f __attribute__((ext_vector_type(4)));

__device__ __forceinline__ float ive_debye(float z) {
    const float inv_v    = (float)(1.0 / 49.5);
    const float c_pref   = 0.05670319f;                  // 1/sqrt(2*pi*49.5)
    const float v_log2e  = 71.41340452f;                 // 49.5 * log2(e)
    const float n_log2e  = -1.4426950408889634f;         // -log2(e)
    const float c1 = (float)(1.0 / (24.0 * 49.5));
    const float c2 = (float)(1.0 / (1152.0 * 49.5 * 49.5));
    const float c3 = (float)(1.0 / (414720.0 * 49.5 * 49.5 * 49.5));
    const float c4 = (float)(1.0 / (39813120.0 * 49.5 * 49.5 * 49.5 * 49.5));

    float x = z * inv_v;
    float q = fmaf(x, x, 1.0f);
    float t = __builtin_amdgcn_rsqf(q);       // 1/sqrt(1+x^2)
    float p = q * t;                           // sqrt(1+x^2)
    float s = t * t;

    // log2(x/(1+p)) via hw rcp + hw log2
    float lg = __builtin_amdgcn_logf(x * __builtin_amdgcn_rcpf(1.0f + p));
    // base-2 exponent: v*log2e*p + v*lg - z*log2e
    float e2 = fmaf(v_log2e, p, fmaf(49.5f, lg, n_log2e * z));

    // u_k(t)/v^k, Horner in s=t^2 (A&S 9.3.9)
    float u1 = c1 * t * fmaf(-5.0f, s, 3.0f);
    float u2 = c2 * s * fmaf(s, fmaf(385.0f, s, -462.0f), 81.0f);
    float u3 = c3 * (t * s) *
               fmaf(s, fmaf(s, fmaf(-425425.0f, s, 765765.0f), -369603.0f), 30375.0f);
    float u4 = c4 * (s * s) *
               fmaf(s, fmaf(s, fmaf(s, fmaf(185910725.0f, s, -446185740.0f),
                                    349922430.0f), -94121676.0f), 4465125.0f);
    float poly = 1.0f + u1 + u2 + u3 + u4;

    float pref = c_pref * __builtin_amdgcn_sqrtf(t);
    return __builtin_amdgcn_exp2f(e2) * pref * poly;
}

__device__ __forceinline__ v4f ive_quad(v4f zv) {
    v4f o;
    o.x = ive_debye(zv.x);
    o.y = ive_debye(zv.y);
    o.z = ive_debye(zv.z);
    o.w = ive_debye(zv.w);
    return o;
}

__global__ __launch_bounds__(256) void ive_kernel(const float* __restrict__ z,
                                                  float* __restrict__ out,
                                                  int half, int n) {
    int i = blockIdx.x * blockDim.x + threadIdx.x;
    if (i < half) {
        const v4f* z4 = (const v4f*)z;
        v4f* o4 = (v4f*)out;
        // issue BOTH nt loads before any compute (MLP=2)
        v4f a = __builtin_nontemporal_load(z4 + i);
        v4f b = __builtin_nontemporal_load(z4 + i + half);
        v4f oa = ive_quad(a);
        __builtin_nontemporal_store(oa, o4 + i);
        v4f ob = ive_quad(b);
        __builtin_nontemporal_store(ob, o4 + i + half);
    }
    if (blockIdx.x == 0 && threadIdx.x == 0) {
        for (int j = half * 8; j < n; ++j) out[j] = ive_debye(z[j]);
    }
}

extern "C" void kernel_launch(void* const* d_in, const int* in_sizes, int n_in,
                              void* d_out, int out_size, void* d_ws, size_t ws_size,
                              hipStream_t stream) {
    const float* z = (const float*)d_in[0];
    float* out = (float*)d_out;
    int n = in_sizes[0];
    int n4 = n >> 2;
    int half = n4 >> 1;               // 2 float4s per thread
    int threads = 256;
    int blocks = (half + threads - 1) / threads;
    if (blocks < 1) blocks = 1;
    ive_kernel<<<blocks, threads, 0, stream>>>(z, out, half, n);
}